// Round 12
// baseline (60.217 us; speedup 1.0000x reference)
//
#include <hip/hip_runtime.h>

typedef unsigned int   u32;
typedef unsigned short u16;
typedef _Float16       f16;

using f16x8  = __attribute__((ext_vector_type(8)))  _Float16;
using f16x4  = __attribute__((ext_vector_type(4)))  _Float16;
using f32x16 = __attribute__((ext_vector_type(16))) float;

#define LLDS16(G, L) __builtin_amdgcn_global_load_lds( \
  (const __attribute__((address_space(1))) u32*)(G), \
  (__attribute__((address_space(3))) u32*)(L), 16, 0, 0)

#define WAITV(N) { asm volatile("s_waitcnt vmcnt(" #N ")" ::: "memory"); \
                   __builtin_amdgcn_sched_barrier(0); }
#define FENCE_BAR() { asm volatile("s_waitcnt lgkmcnt(0)" ::: "memory"); \
                      __builtin_amdgcn_sched_barrier(0); \
                      __builtin_amdgcn_s_barrier(); \
                      __builtin_amdgcn_sched_barrier(0); }
#define BAR() { __builtin_amdgcn_s_barrier(); __builtin_amdgcn_sched_barrier(0); }
#define KEEP(x) asm volatile("" : "+v"(x))

// ---- merged prep: [bid<2560] x transpose+sums; [else] W0/W1 k-panel ----
__global__ __launch_bounds__(256)
void prep(const float* __restrict__ x,
          const float* __restrict__ W0, const float* __restrict__ W1,
          f16* __restrict__ xt, f16* __restrict__ W0p, f16* __restrict__ W1p,
          float* __restrict__ out){
  __shared__ char shm[33920];
  const int tid = threadIdx.x;
  if (blockIdx.x < 2560){
    float (*tile)[33] = (float(*)[33])shm;
    const int r0 = blockIdx.x << 5;
    const int c  = tid & 31;
    const int rp = tid >> 5;
#pragma unroll
    for (int p = 0; p < 4; ++p){
      const int r = (p << 3) + rp;
      float v = x[(size_t)(r0 + r) * 32 + c];
      tile[r][c] = v;
      float s = v;
#pragma unroll
      for (int off = 16; off > 0; off >>= 1) s += __shfl_xor(s, off, 32);
      if (c == 0){
        const int row = r0 + r;            // = b*40 + f
        out[(size_t)(row / 40) * 168 + (row % 40)] = s;
      }
    }
    __syncthreads();
#pragma unroll
    for (int p = 0; p < 4; ++p){
      const int dd = (p << 3) + rp;
      xt[(size_t)dd * 81920 + r0 + c] = (f16)tile[c][dd];
    }
  } else {
    u16* t = (u16*)shm;
    int kb = blockIdx.x - 2560;
    const float* in; f16* outp; int K;
    if (kb < 200){ in = W0; outp = W0p; K = 1600; }
    else         { kb -= 200; in = W1; outp = W1p; K = 2560; }
    const int kbase = kb << 3;
#pragma unroll 4
    for (int i = 0; i < 64; ++i){
      const int idx = tid + (i << 8);
      const int o   = idx >> 8;
      const int rem = idx & 255;
      const int e   = rem >> 5;
      const int dd  = rem & 31;
      const float v = in[(size_t)o * (K * 32) + (size_t)(kbase + e) * 32 + dd];
      union { f16 h; u16 u; } cv; cv.h = (f16)v;
      t[dd * 530 + o * 8 + e] = cv.u;
    }
    __syncthreads();
    const u32* t32 = (const u32*)t;
    u32* o32 = (u32*)outp;
    const int obase = kb << 8;
#pragma unroll 4
    for (int i = 0; i < 32; ++i){
      const int idx = tid + (i << 8);
      const int dd  = idx >> 8;
      const int rem = idx & 255;
      o32[(size_t)dd * (K * 32) + obase + rem] = t32[dd * 265 + rem];
    }
  }
}

// -------- fused CIN: 32x32x16, 32-row waves, 16 waves/CU for latency hiding --
// Block: 128 rows x 64 cols x one d, 8 waves (4 rowgroups x 2 colhalves).
// BK=160; 26 B-tiles (10 W0 + 16 W1) stream through dbuf LDS, counted vmcnt.
// x0 LDS overlaid by x1 (phase2) overlaid by y-staging (epilogue2).
__global__ __launch_bounds__(512, 4)
void cin_fused(const f16* __restrict__ xt,     // [32][2048*40] f16
               const f16* __restrict__ W0p,    // [32][200][64][8] f16
               const f16* __restrict__ W1p,    // [32][320][64][8] f16
               const float* __restrict__ b0v, const float* __restrict__ b1v,
               f16* __restrict__ x1s,          // [2048][32][64] f16
               f16* __restrict__ y2s){         // [2048][32][64] f16
  constexpr int XOFF = 40960;           // after 2 x 20KB B dbuf; x0 then x1 here

  const int bid = blockIdx.x;
  const int d   = ((bid & 7) << 2) | ((bid >> 3) & 3);   // XCD-local d groups
  const int b0  = (bid >> 5) << 7;      // 16 b-tiles of 128 rows
  const int tid = threadIdx.x;
  const int wv  = tid >> 6;             // 0..7
  const int rg  = wv >> 1;              // rowgroup (32 rows)
  const int wc  = wv & 1;               // col half (32 cols)
  const int l   = tid & 63;
  const int hi  = l >> 5;               // k-run half
  const int lr  = l & 31;

  __shared__ char smem[59392];

  const f16* gW0 = W0p + (size_t)d * 102400;
  const f16* gW1 = W1p + (size_t)d * 163840;

  // W tile = 20480B = 20 x 1KB chunks; wave wv loads chunks {wv, 8+wv, [16+wv]}
#define ISSUE(I) do { \
    const f16* src_ = ((I) < 10) ? (gW0 + (size_t)(I) * 10240) \
                                 : (gW1 + (size_t)((I) - 10) * 10240); \
    const f16* gt_ = src_ + l * 8; \
    char* lb_ = smem + ((I) & 1) * 20480; \
    LLDS16(gt_ + (size_t)wv * 512,       lb_ + wv * 1024); \
    LLDS16(gt_ + (size_t)(8 + wv) * 512, lb_ + (8 + wv) * 1024); \
    if (wv < 4) LLDS16(gt_ + (size_t)(16 + wv) * 512, lb_ + (16 + wv) * 1024); \
  } while (0)
#define WAITVP() { if (wv < 4) { WAITV(3); } else { WAITV(2); } }

  ISSUE(0);
  ISSUE(1);

  { // stage x0 tile: 128 rows * 80B -> stride 96B
    const uint4* src = (const uint4*)(xt + (size_t)d * 81920 + (size_t)b0 * 40);
#pragma unroll
    for (int it = 0; it < 2; ++it){
      const int idx = tid + (it << 9);
      if (idx < 640){
        const int r = idx / 5, c = idx - r * 5;
        *(uint4*)(smem + XOFF + r * 96 + c * 16) = src[idx];
      }
    }
  }
  __syncthreads();                      // drains vmcnt: tiles 0,1 + x0 landed

  const char* x0r = smem + XOFF + ((rg << 5) + lr) * 96;
  const char* x1r = smem + XOFF + ((rg << 5) + lr) * 144;
  const int   col = (wc << 5) + lr;
  const float bv1 = b0v[col];
  const float bv2 = b1v[col];

  // sl[s] = x0 f-block (s+hi)%5 of this lane's row (pinned in VGPRs)
  f16x8 sl[5];
  {
    const char* xe = x0r + hi * 16;
#pragma unroll
    for (int t = 0; t < 4; ++t) sl[t] = *(const f16x8*)(xe + t * 16);
    sl[4] = *(const f16x8*)(x0r + (hi ? 0 : 64));
  }
  KEEP(sl[0]); KEEP(sl[1]); KEEP(sl[2]); KEEP(sl[3]); KEEP(sl[4]);

  f32x16 acc = {0,0,0,0,0,0,0,0,0,0,0,0,0,0,0,0};

  const int vb = (hi << 10) + (wc << 9) + (lr << 4);

  // r8 = si*4 + 2p + hi; slot = (si*4+2p)%5 (hi-rotated sl); h-elem tables
  static constexpr int J0[5]  = {0, 4, 3, 2, 1};
  static constexpr int H0[5]  = {0, 0, 1, 2, 3};
  static constexpr int H0b[5] = {0, 1, 1, 2, 3};
  static constexpr int S0[5]  = {0, 1, 0, 0, 0};
  static constexpr int J2[5]  = {2, 1, 0, 4, 3};
  static constexpr int H2[5]  = {0, 1, 2, 2, 3};
  static constexpr int H2b[5] = {0, 1, 2, 3, 3};
  static constexpr int S2[5]  = {0, 0, 0, 1, 0};

#define COMP(BB) do { \
  __builtin_amdgcn_s_setprio(1); \
  _Pragma("unroll") \
  for (int si = 0; si < 5; ++si){ \
    const f16x8 bf0 = *(const f16x8*)((BB) + vb + si * 4096); \
    const f16x8 bf2 = *(const f16x8*)((BB) + vb + si * 4096 + 2048); \
    const f16 xa0 = (S0[si] && hi) ? xh[H0b[si]] : xh[H0[si]]; \
    const f16 xa2 = (S2[si] && hi) ? xh[H2b[si]] : xh[H2[si]]; \
    acc = __builtin_amdgcn_mfma_f32_32x32x16_f16(sl[J0[si]] * xa0, bf0, acc, 0, 0, 0); \
    acc = __builtin_amdgcn_mfma_f32_32x32x16_f16(sl[J2[si]] * xa2, bf2, acc, 0, 0, 0); \
  } \
  __builtin_amdgcn_s_setprio(0); \
} while (0)

  // ---------------- phase 1: xk = x0, 10 tiles ----------------
  {
    f16x4 xh = *(const f16x4*)(x0r);
    for (int t = 0; t < 10; ++t){
      const char* bb = smem + (t & 1) * 20480;
      const f16x4 xhn = *(const f16x4*)(x0r + (t + 1) * 8);   // pad-safe
      COMP(bb);
      FENCE_BAR();
      ISSUE(t + 2);                     // tiles 2..11 (10,11 are W1 tiles 0,1)
      WAITVP();                         // tile t+1 landed
      BAR();
      xh = xhn;
    }
  }

  // ---- epilogue 1: x1 -> LDS (overlay x0), coalesced partial store ----
  {
    u16* x1w = (u16*)(smem + XOFF);
#pragma unroll
    for (int reg = 0; reg < 16; ++reg){
      const int row = (rg << 5) + (reg & 3) + ((reg >> 2) << 3) + (hi << 2);
      float v = acc[reg] + bv1;
      v = v > 0.f ? v : 0.f;
      union { f16 h; u16 u; } cv; cv.h = (f16)v;
      x1w[row * 72 + col] = cv.u;
      acc[reg] = 0.f;
    }
    asm volatile("s_waitcnt lgkmcnt(0)" ::: "memory");
    __builtin_amdgcn_sched_barrier(0);
    BAR();                              // x1 tile visible to all waves
#pragma unroll
    for (int it = 0; it < 2; ++it){
      const int u   = tid + (it << 9);
      const int row = u >> 3, ch = u & 7;
      const f16x8 vv = *(const f16x8*)((const char*)x1w + row * 144 + ch * 16);
      *(f16x8*)(x1s + (size_t)(b0 + row) * 2048 + d * 64 + ch * 8) = vv;
    }
  }

  // ---------------- phase 2: xk = x1 (LDS), 16 tiles ----------------
  {
    f16x4 xh = *(const f16x4*)(x1r);
    for (int t = 0; t < 16; ++t){
      const char* bb = smem + (t & 1) * 20480;        // tile 10+t, 10 even
      const f16x4 xhn = *(const f16x4*)(x1r + (t + 1) * 8);   // pad-safe
      COMP(bb);
      FENCE_BAR();
      if (t + 2 < 16){
        ISSUE(12 + t);
        WAITVP();                       // also drains epilogue-1 stores once
      } else {
        WAITV(0);
      }
      BAR();
      xh = xhn;
    }
  }

  // ---- epilogue 2: y2 -> LDS (overlay x1) -> coalesced partial store ----
  {
    u16* yw = (u16*)(smem + XOFF);
#pragma unroll
    for (int reg = 0; reg < 16; ++reg){
      const int row = (rg << 5) + (reg & 3) + ((reg >> 2) << 3) + (hi << 2);
      float v = acc[reg] + bv2;
      v = v > 0.f ? v : 0.f;
      union { f16 h; u16 u; } cv; cv.h = (f16)v;
      yw[row * 72 + col] = cv.u;
    }
    asm volatile("s_waitcnt lgkmcnt(0)" ::: "memory");
    __builtin_amdgcn_sched_barrier(0);
    BAR();
#pragma unroll
    for (int it = 0; it < 2; ++it){
      const int u   = tid + (it << 9);
      const int row = u >> 3, ch = u & 7;
      const f16x8 vv = *(const f16x8*)((const char*)yw + row * 144 + ch * 16);
      *(f16x8*)(y2s + (size_t)(b0 + row) * 2048 + d * 64 + ch * 8) = vv;
    }
  }
#undef ISSUE
#undef WAITVP
#undef COMP
}

// ------- final: out[b, 40:168] = sum_d concat(x1, y2), coalesced reads -------
__global__ __launch_bounds__(128)
void finalize(const f16* __restrict__ x1s, const f16* __restrict__ y2s,
              float* __restrict__ out){
  const int b = blockIdx.x;
  const int t = threadIdx.x;
  if (t < 64){
    float s = 0.f;
#pragma unroll
    for (int d = 0; d < 32; ++d) s += (float)x1s[(size_t)b * 2048 + d * 64 + t];
    out[(size_t)b * 168 + 40 + t] = s;
  } else {
    const int o = t - 64;
    float s = 0.f;
#pragma unroll
    for (int d = 0; d < 32; ++d) s += (float)y2s[(size_t)b * 2048 + d * 64 + o];
    out[(size_t)b * 168 + 104 + o] = s;
  }
}

extern "C" void kernel_launch(void* const* d_in, const int* in_sizes, int n_in,
                              void* d_out, int out_size, void* d_ws, size_t ws_size,
                              hipStream_t stream){
  const float* x   = (const float*)d_in[0];
  const float* W0  = (const float*)d_in[1];
  const float* b0v = (const float*)d_in[2];
  const float* W1  = (const float*)d_in[3];
  const float* b1v = (const float*)d_in[4];
  float* out = (float*)d_out;

  char* ws = (char*)d_ws;
  f16* xt  = (f16*)(ws + 0);            // 32*2048*40*2  =  5,242,880
  f16* W0p = (f16*)(ws + 5242880);      // 32*64*1600*2  =  6,553,600
  f16* W1p = (f16*)(ws + 11796480);     // 32*64*2560*2  = 10,485,760
  f16* x1s = (f16*)(ws + 22282240);     // 2048*32*64*2  =  8,388,608
  f16* y2s = (f16*)(ws + 30670848);     // 2048*32*64*2  =  8,388,608

  prep<<<3080, 256, 0, stream>>>(x, W0, W1, xt, W0p, W1p, out);
  cin_fused<<<512, 512, 0, stream>>>(xt, W0p, W1p, b0v, b1v, x1s, y2s);
  finalize<<<2048, 128, 0, stream>>>(x1s, y2s, out);
}